// Round 4
// baseline (56.869 us; speedup 1.0000x reference)
//
#include <hip/hip_runtime.h>

#define N_IMG 8
#define CIN   128
#define H_IN  56
#define W_IN  56
#define COUT  128
#define HW    3136
#define NCHUNK 9

typedef __attribute__((ext_vector_type(8))) short short8;
typedef __attribute__((ext_vector_type(4))) float f32x4;

__device__ __forceinline__ unsigned short f2b(float f) {
    unsigned u = __builtin_bit_cast(unsigned, f);
    u = u + 0x7FFFu + ((u >> 16) & 1u);
    return (unsigned short)(u >> 16);
}
__device__ __forceinline__ float b2f(unsigned short h) {
    unsigned u = ((unsigned)h) << 16;
    return __builtin_bit_cast(float, u);
}
__device__ __forceinline__ void gload16(const void* g, void* l) {
    __builtin_amdgcn_global_load_lds(
        (const __attribute__((address_space(1))) unsigned int*)g,
        (__attribute__((address_space(3))) unsigned int*)l, 16, 0, 0);
}

// blocks 0..783: x (N,C,H,W) f32 -> xt (N,H,W,C) bf16
// blocks 784..855: weight -> wr[step][frag][lane][8] bf16 (MFMA B-fragment-linear)
__global__ __launch_bounds__(256) void prep_kernel(const float* __restrict__ x,
                                                   const float* __restrict__ w,
                                                   unsigned short* __restrict__ xt,
                                                   unsigned short* __restrict__ wr) {
    int b = blockIdx.x;
    int tid = threadIdx.x;
    if (b < 784) {
        int c = tid & 127;
        int half = tid >> 7;
        int n = b / 98;
        int hw0 = (b - n * 98) * 32 + half * 16;
        const float* xp = x + ((size_t)(n * CIN + c)) * HW + hw0;
        unsigned short* op = xt + ((size_t)n * HW + hw0) * CIN + c;
#pragma unroll
        for (int r = 0; r < 16; ++r) op[r * CIN] = f2b(xp[r]);
    } else {
        int idx = (b - 784) * 256 + tid;        // 0..18431 = 36*8*64
        int lane = idx & 63;
        int f = (idx >> 6) & 7;
        int step = idx >> 9;
        int tap = step >> 2;
        int c0 = (step & 3) << 5;
        int cout = f * 16 + (lane & 15);
        int cb = c0 + (lane >> 4) * 8;
        short8 v;
#pragma unroll
        for (int j = 0; j < 8; ++j)
            v[j] = (short)f2b(w[((size_t)cout * CIN + cb + j) * 9 + tap]);
        *(short8*)(wr + (size_t)idx * 8) = v;
    }
}

__global__ __launch_bounds__(512, 4) void deform_main(
    const float* __restrict__ offset, const float* __restrict__ x2,
    const float* __restrict__ bias, const unsigned short* __restrict__ xt,
    const unsigned short* __restrict__ wr, float* __restrict__ out)
{
    __shared__ int4   lin_lds[9 * 32];
    __shared__ float4 wt_lds[9 * 32];
    __shared__ short  bbuf[2][4][4096];   // double-buffered chunk of 4 B step-tiles

    int tid = threadIdx.x;
    int orig = blockIdx.x;                // 784 = 8 * 98; one image per XCD
    int swz = (orig & 7) * 98 + (orig >> 3);
    int pix0 = swz * 32;
    int n = pix0 / HW;
    int hw0 = pix0 - n * HW;

    // ---- bilinear params: 288 = 9 taps x 32 pixels ----
    if (tid < 9 * 32) {
        int tap = tid >> 5;
        int pl  = tid & 31;
        int hw = hw0 + pl;
        int ho = hw / W_IN;
        int wo = hw - ho * W_IN;
        const float* offp = offset + ((size_t)n * 18 + tap * 2) * HW + hw;
        float offy = offp[0];
        float offx = offp[HW];
        int ki = tap / 3;
        int kj = tap - ki * 3;
        float py = (float)(ho - 1 + ki) + offy;
        float px = (float)(wo - 1 + kj) + offx;
        float y0f = floorf(py), x0f = floorf(px);
        float wy = py - y0f, wx = px - x0f;
        int y0 = (int)y0f, x0 = (int)x0f;
        int y1 = y0 + 1, x1 = x0 + 1;
        bool vy0 = (y0 >= 0) && (y0 < H_IN);
        bool vy1 = (y1 >= 0) && (y1 < H_IN);
        bool vx0 = (x0 >= 0) && (x0 < W_IN);
        bool vx1 = (x1 >= 0) && (x1 < W_IN);
        int cy0 = min(max(y0, 0), H_IN - 1), cy1 = min(max(y1, 0), H_IN - 1);
        int cx0 = min(max(x0, 0), W_IN - 1), cx1 = min(max(x1, 0), W_IN - 1);
        int4 lv;
        lv.x = (cy0 * W_IN + cx0) * (CIN * 2);
        lv.y = (cy0 * W_IN + cx1) * (CIN * 2);
        lv.z = (cy1 * W_IN + cx0) * (CIN * 2);
        lv.w = (cy1 * W_IN + cx1) * (CIN * 2);
        float4 wv;
        wv.x = (vy0 && vx0) ? (1.f - wy) * (1.f - wx) : 0.f;
        wv.y = (vy0 && vx1) ? (1.f - wy) * wx : 0.f;
        wv.z = (vy1 && vx0) ? wy * (1.f - wx) : 0.f;
        wv.w = (vy1 && vx1) ? wy * wx : 0.f;
        lin_lds[tid] = lv;
        wt_lds[tid] = wv;
    }

    int lane = tid & 63;
    int w8 = tid >> 6;        // wave 0..7
    int pg = w8 & 1;          // pixel group (16 px)
    int kg = w8 >> 1;         // K group (channel quarter, all 9 taps)
    int llo = lane & 15, lhi = lane >> 4;
    int mypix = pg * 16 + llo;
    const char* xb = (const char*)(xt + (size_t)n * HW * CIN);

    f32x4 acc[8] = {};
    short8 gc[4], gn[4];

    auto STAGE = [&](int c) {   // stage 4 step-tiles (32KB) of chunk c
        int buf = c & 1;
#pragma unroll
        for (int j = 0; j < 4; ++j)
            gload16(wr + ((size_t)(c * 4 + j) * 4096 + w8 * 512 + lane * 8),
                    &bbuf[buf][j][w8 * 512]);
    };
    auto GATHER = [&](int c, short8* g) {   // tap c, channel quarter kg
        int4 lv = lin_lds[c * 32 + mypix];
        const char* bp = xb + ((kg * 32 + lhi * 8) << 1);
        g[0] = *(const short8*)(bp + lv.x);
        g[1] = *(const short8*)(bp + lv.y);
        g[2] = *(const short8*)(bp + lv.z);
        g[3] = *(const short8*)(bp + lv.w);
    };

    // prologue
    STAGE(0);
    __syncthreads();          // params visible; stage(0) drained by vmcnt(0)
    GATHER(0, gc);

    for (int c = 0; c < NCHUNK; ++c) {
        if (c + 1 < NCHUNK) {
            STAGE(c + 1);     // into other buffer; drains at end barrier
            GATHER(c + 1, gn);
        }
        // B fragments for this wave's step (tile kg of chunk c)
        const short* bb = &bbuf[c & 1][kg][0];
        short8 bf[8];
#pragma unroll
        for (int f = 0; f < 8; ++f)
            bf[f] = *(const short8*)(bb + f * 512 + lane * 8);
        // interp -> A fragment (registers, MFMA layout)
        float4 w4 = wt_lds[c * 32 + mypix];
        short8 a;
#pragma unroll
        for (int j = 0; j < 8; ++j) {
            float r = w4.x * b2f((unsigned short)gc[0][j])
                    + w4.y * b2f((unsigned short)gc[1][j])
                    + w4.z * b2f((unsigned short)gc[2][j])
                    + w4.w * b2f((unsigned short)gc[3][j]);
            a[j] = (short)f2b(r);
        }
#pragma unroll
        for (int f = 0; f < 8; ++f)
            acc[f] = __builtin_amdgcn_mfma_f32_16x16x32_bf16(a, bf[f], acc[f], 0, 0, 0);
        __syncthreads();      // chunk c reads done WG-wide; stage(c+1) visible
        if (c + 1 < NCHUNK) {
#pragma unroll
            for (int q = 0; q < 4; ++q) gc[q] = gn[q];
        }
    }

    // ---- split-K reduction: kg 1..3 -> kg 0 via LDS (conflict-free layout) ----
    float* red = (float*)&bbuf[0][0][0];   // 16KB scratch
#pragma unroll
    for (int g = 1; g < 4; ++g) {
        __syncthreads();
        if (kg == g) {
#pragma unroll
            for (int f = 0; f < 8; ++f)
                *(f32x4*)&red[((pg * 8 + f) * 64 + lane) * 4] = acc[f];
        }
        __syncthreads();
        if (kg == 0) {
#pragma unroll
            for (int f = 0; f < 8; ++f)
                acc[f] += *(const f32x4*)&red[((pg * 8 + f) * 64 + lane) * 4];
        }
    }

    // ---- epilogue (kg==0 waves): + bias + x2, ReLU, f32x4 stores ----
    if (kg == 0) {
        int hwb = hw0 + pg * 16 + lhi * 4;
#pragma unroll
        for (int f = 0; f < 8; ++f) {
            int cout = f * 16 + llo;
            float bb = bias[cout];
            size_t off = ((size_t)(n * COUT + cout)) * HW + hwb;
            f32x4 xv = *(const f32x4*)(x2 + off);
            f32x4 o;
#pragma unroll
            for (int r = 0; r < 4; ++r) {
                float v = acc[f][r] + bb + xv[r];
                o[r] = v > 0.f ? v : 0.f;
            }
            *(f32x4*)(out + off) = o;
        }
    }
}

extern "C" void kernel_launch(void* const* d_in, const int* in_sizes, int n_in,
                              void* d_out, int out_size, void* d_ws, size_t ws_size,
                              hipStream_t stream) {
    const float* x      = (const float*)d_in[0];
    const float* offset = (const float*)d_in[1];
    const float* weight = (const float*)d_in[2];
    const float* bias   = (const float*)d_in[3];
    const float* x2     = (const float*)d_in[4];
    float* out = (float*)d_out;

    const size_t XT_BYTES = (size_t)N_IMG * HW * CIN * 2;   // 6,422,528
    unsigned short* xt = (unsigned short*)d_ws;
    unsigned short* wr = (unsigned short*)((char*)d_ws + XT_BYTES);

    prep_kernel<<<856, 256, 0, stream>>>(x, weight, xt, wr);
    deform_main<<<784, 512, 0, stream>>>(offset, x2, bias, xt, wr, out);
}

// Round 5
// 47.468 us; speedup vs baseline: 1.1980x; 1.1980x over previous
//
#include <hip/hip_runtime.h>

#define N_IMG 8
#define CIN   128
#define H_IN  56
#define W_IN  56
#define COUT  128
#define HW    3136
#define TROWS 8                       // tile rows [ho-3, ho+4]
#define TILE_BYTES (TROWS * 56 * 256) // 114688
#define PMC_OFF  TILE_BYTES
#define PMW_OFF  (TILE_BYTES + 2304)
#define BLDS_OFF (TILE_BYTES + 2304 + 9216)
#define SMEM_TOTAL (BLDS_OFF + 32768) // 158976 <= 163840

typedef __attribute__((ext_vector_type(8))) short short8;
typedef __attribute__((ext_vector_type(4))) float f32x4;

__device__ __forceinline__ unsigned short f2b(float f) {
    unsigned u = __builtin_bit_cast(unsigned, f);
    u = u + 0x7FFFu + ((u >> 16) & 1u);
    return (unsigned short)(u >> 16);
}
__device__ __forceinline__ float b2f(unsigned short h) {
    unsigned u = ((unsigned)h) << 16;
    return __builtin_bit_cast(float, u);
}
__device__ __forceinline__ void gload16(const void* g, void* l) {
    __builtin_amdgcn_global_load_lds(
        (const __attribute__((address_space(1))) unsigned int*)g,
        (__attribute__((address_space(3))) unsigned int*)l, 16, 0, 0);
}

// blocks 0..783: x (N,C,H,W) f32 -> xt (N,H,W,C) bf16 (linear NHWC)
// blocks 784..855: weight -> wr[tap][kg][f][lane][8] bf16 (B-fragment-linear)
__global__ __launch_bounds__(256) void prep_kernel(const float* __restrict__ x,
                                                   const float* __restrict__ w,
                                                   unsigned short* __restrict__ xt,
                                                   unsigned short* __restrict__ wr) {
    int b = blockIdx.x;
    int tid = threadIdx.x;
    if (b < 784) {
        int c = tid & 127;
        int half = tid >> 7;
        int n = b / 98;
        int hw0 = (b - n * 98) * 32 + half * 16;
        const float* xp = x + ((size_t)(n * CIN + c)) * HW + hw0;
        unsigned short* op = xt + ((size_t)n * HW + hw0) * CIN + c;
#pragma unroll
        for (int r = 0; r < 16; ++r) op[r * CIN] = f2b(xp[r]);
    } else {
        int idx = (b - 784) * 256 + tid;        // 0..18431 = 36*8*64
        int lane = idx & 63;
        int f = (idx >> 6) & 7;
        int step = idx >> 9;                    // tap*4 + kg
        int tap = step >> 2;
        int c0 = (step & 3) << 5;
        int cout = f * 16 + (lane & 15);
        int cb = c0 + (lane >> 4) * 8;
        short8 v;
#pragma unroll
        for (int j = 0; j < 8; ++j)
            v[j] = (short)f2b(w[((size_t)cout * CIN + cb + j) * 9 + tap]);
        *(short8*)(wr + (size_t)idx * 8) = v;
    }
}

__global__ __launch_bounds__(1024, 4) void deform_main(
    const float* __restrict__ offset, const float* __restrict__ x2,
    const float* __restrict__ bias, const unsigned short* __restrict__ xt,
    const unsigned short* __restrict__ wr, float* __restrict__ out)
{
    extern __shared__ char smem[];
    int*    pmc = (int*)(smem + PMC_OFF);      // packed corner coords+flags [576]
    float4* pmw = (float4*)(smem + PMW_OFF);   // bilinear weights [576]
    char*   blds = smem + BLDS_OFF;            // 32KB per-tap B slice

    int tid = threadIdx.x;
    int orig = blockIdx.x;                     // 448 = 8 * 56
    int n  = orig & 7;                         // XCD-bijective: image per XCD
    int ho = orig >> 3;

    int lane = tid & 63;
    int w16 = tid >> 6;                        // wave 0..15
    int kg = w16 & 3;                          // K quarter (32 ch)
    int mt = w16 >> 2;                         // M tile (16 px)
    int llo = lane & 15, lhi = lane >> 4;
    int cbase = kg * 4 + lhi;                  // 16B-chunk index within 256B px block

    const char* xim = (const char*)(xt + (size_t)n * HW * CIN);

    // ---- stage 8x56x128ch tile, swizzled (slot = chunk ^ (p&15)) ----
#pragma unroll
    for (int s = 0; s < 7; ++s) {
        int d = (s * 16 + w16) * 1024 + lane * 16;
        int p = d >> 8;                        // tile-linear pixel 0..447
        int tr = p / 56;
        int tx = p - tr * 56;
        int gy = min(max(ho - 3 + tr, 0), 55);
        int c  = ((d >> 4) & 15) ^ (p & 15);
        gload16(xim + (((gy * 56 + tx) << 8) + (c << 4)), smem + d);
    }

    // ---- bilinear params: 576 = 9 taps x 64 px (px>=56 duplicates px 55) ----
    if (tid < 576) {
        int tap = tid >> 6;
        int px  = tid & 63;
        int wo  = min(px, 55);
        const float* offp = offset + ((size_t)n * 18 + tap * 2) * HW + ho * 56 + wo;
        float offy = offp[0];
        float offx = offp[HW];
        int ki = tap / 3;
        int kj = tap - ki * 3;
        float py = (float)(ho - 1 + ki) + offy;
        float pxf = (float)(wo - 1 + kj) + offx;
        float y0f = floorf(py), x0f = floorf(pxf);
        float wy = py - y0f, wx = pxf - x0f;
        int y0 = (int)y0f, x0 = (int)x0f;
        int y1 = y0 + 1, x1 = x0 + 1;
        bool vy0 = (y0 >= 0) && (y0 < H_IN);
        bool vy1 = (y1 >= 0) && (y1 < H_IN);
        bool vx0 = (x0 >= 0) && (x0 < W_IN);
        bool vx1 = (x1 >= 0) && (x1 < W_IN);
        int cy0 = min(max(y0, 0), 55), cy1 = min(max(y1, 0), 55);
        int cx0 = min(max(x0, 0), 55), cx1 = min(max(x1, 0), 55);
        int f0 = (y0 < ho - 3 || y0 > ho + 4) ? 1 : 0;   // y0 outside tile
        int f1 = (y1 < ho - 3 || y1 > ho + 4) ? 1 : 0;
        pmc[tid] = cy0 | (cy1 << 6) | (cx0 << 12) | (cx1 << 18) | (f0 << 24) | (f1 << 25);
        float4 wv;
        wv.x = (vy0 && vx0) ? (1.f - wy) * (1.f - wx) : 0.f;
        wv.y = (vy0 && vx1) ? (1.f - wy) * wx : 0.f;
        wv.z = (vy1 && vx0) ? wy * (1.f - wx) : 0.f;
        wv.w = (vy1 && vx1) ? wy * wx : 0.f;
        pmw[tid] = wv;
    }

    // ---- T14 B prologue: tap-0 slice to regs ----
    const char* wrt = (const char*)wr;
    short8 br0 = *(const short8*)(wrt + tid * 32);
    short8 br1 = *(const short8*)(wrt + tid * 32 + 16);

    __syncthreads();   // tile + params visible

    f32x4 acc[8] = {};

    for (int tap = 0; tap < 9; ++tap) {
        // write this tap's B slice to LDS
        *(short8*)(blds + tid * 32)      = br0;
        *(short8*)(blds + tid * 32 + 16) = br1;
        __syncthreads();
        if (tap < 8) {   // issue next tap's B loads; land during compute below
            br0 = *(const short8*)(wrt + (size_t)(tap + 1) * 32768 + tid * 32);
            br1 = *(const short8*)(wrt + (size_t)(tap + 1) * 32768 + tid * 32 + 16);
        }

        int cw = pmc[tap * 64 + mt * 16 + llo];
        float4 W = pmw[tap * 64 + mt * 16 + llo];
        int cy0 = cw & 63, cy1 = (cw >> 6) & 63;
        int cx0 = (cw >> 12) & 63, cx1 = (cw >> 18) & 63;
        int f0 = (cw >> 24) & 1, f1 = (cw >> 25) & 1;

        short8 g0, g1, g2, g3;
        {
            int tr, p, slot;
            tr = min(max(cy0 + 3 - ho, 0), TROWS - 1);
            p = tr * 56 + cx0; slot = cbase ^ (p & 15);
            g0 = *(const short8*)(smem + (p << 8) + (slot << 4));
            p = tr * 56 + cx1; slot = cbase ^ (p & 15);
            g1 = *(const short8*)(smem + (p << 8) + (slot << 4));
            tr = min(max(cy1 + 3 - ho, 0), TROWS - 1);
            p = tr * 56 + cx0; slot = cbase ^ (p & 15);
            g2 = *(const short8*)(smem + (p << 8) + (slot << 4));
            p = tr * 56 + cx1; slot = cbase ^ (p & 15);
            g3 = *(const short8*)(smem + (p << 8) + (slot << 4));
        }
        // rare fallback: corner has nonzero weight but lies outside the tile rows
        bool b0 = f0 && (W.x != 0.f), b1 = f0 && (W.y != 0.f);
        bool b2 = f1 && (W.z != 0.f), b3 = f1 && (W.w != 0.f);
        if (__any(b0 | b1 | b2 | b3)) {
            if (b0) g0 = *(const short8*)(xim + ((size_t)(cy0 * 56 + cx0) << 8) + (cbase << 4));
            if (b1) g1 = *(const short8*)(xim + ((size_t)(cy0 * 56 + cx1) << 8) + (cbase << 4));
            if (b2) g2 = *(const short8*)(xim + ((size_t)(cy1 * 56 + cx0) << 8) + (cbase << 4));
            if (b3) g3 = *(const short8*)(xim + ((size_t)(cy1 * 56 + cx1) << 8) + (cbase << 4));
        }

        short8 a;
#pragma unroll
        for (int j = 0; j < 8; ++j) {
            float r = W.x * b2f((unsigned short)g0[j])
                    + W.y * b2f((unsigned short)g1[j])
                    + W.z * b2f((unsigned short)g2[j])
                    + W.w * b2f((unsigned short)g3[j]);
            a[j] = (short)f2b(r);
        }
#pragma unroll
        for (int f = 0; f < 8; ++f) {
            short8 bf = *(const short8*)(blds + (kg * 8 + f) * 1024 + lane * 16);
            acc[f] = __builtin_amdgcn_mfma_f32_16x16x32_bf16(a, bf, acc[f], 0, 0, 0);
        }
        __syncthreads();   // all B reads done; safe to overwrite next iter
    }

    // ---- split-K reduction over kg (LDS, reuse tile region) ----
    float* red = (float*)smem;
    if (kg > 0) {
#pragma unroll
        for (int f = 0; f < 8; ++f)
            *(f32x4*)&red[((((kg - 1) * 4 + mt) * 8 + f) * 64 + lane) * 4] = acc[f];
    }
    __syncthreads();
    if (kg == 0) {
#pragma unroll
        for (int g = 0; g < 3; ++g)
#pragma unroll
            for (int f = 0; f < 8; ++f)
                acc[f] += *(const f32x4*)&red[(((g * 4 + mt) * 8 + f) * 64 + lane) * 4];

        // ---- epilogue: + bias + x2, ReLU ----
        int wo4 = mt * 16 + lhi * 4;
        if (wo4 < 56) {
#pragma unroll
            for (int f = 0; f < 8; ++f) {
                int cout = f * 16 + llo;
                float bb = bias[cout];
                size_t off = ((size_t)(n * COUT + cout)) * HW + ho * 56 + wo4;
                f32x4 xv = *(const f32x4*)(x2 + off);
                f32x4 o;
#pragma unroll
                for (int r = 0; r < 4; ++r) {
                    float v = acc[f][r] + bb + xv[r];
                    o[r] = v > 0.f ? v : 0.f;
                }
                *(f32x4*)(out + off) = o;
            }
        }
    }
}

extern "C" void kernel_launch(void* const* d_in, const int* in_sizes, int n_in,
                              void* d_out, int out_size, void* d_ws, size_t ws_size,
                              hipStream_t stream) {
    const float* x      = (const float*)d_in[0];
    const float* offset = (const float*)d_in[1];
    const float* weight = (const float*)d_in[2];
    const float* bias   = (const float*)d_in[3];
    const float* x2     = (const float*)d_in[4];
    float* out = (float*)d_out;

    const size_t XT_BYTES = (size_t)N_IMG * HW * CIN * 2;   // 6,422,528
    unsigned short* xt = (unsigned short*)d_ws;
    unsigned short* wr = (unsigned short*)((char*)d_ws + XT_BYTES);

    prep_kernel<<<856, 256, 0, stream>>>(x, weight, xt, wr);
    hipFuncSetAttribute((const void*)deform_main,
                        hipFuncAttributeMaxDynamicSharedMemorySize, SMEM_TOTAL);
    deform_main<<<448, 1024, SMEM_TOTAL, stream>>>(offset, x2, bias, xt, wr, out);
}